// Round 1
// baseline (2121.372 us; speedup 1.0000x reference)
//
#include <hip/hip_runtime.h>
#include <math.h>

#define BB 256
#define SS 256
#define CQKV 128
#define NH 4
#define CH 32
#define HC 128

// ---------------------------------------------------------------------------
// K1: fused QKVG projection.  qkvg[b,s,f] = sum_c X[b,s,c] * W[f,c]
// One block per b (256 threads = one per s). X row lives in VGPRs; W is read
// through the scalar path (index is wave-uniform). Fuses q-scale and
// sigmoid gate. Outputs layout [b][h][s][32] fp32.
// ---------------------------------------------------------------------------
__global__ __launch_bounds__(256, 2) void k1_qkvg(
    const float* __restrict__ X,      // [B][S][128]
    const float* __restrict__ W,      // [512][128]
    const float* __restrict__ gbias,  // [128]
    float* __restrict__ Qws, float* __restrict__ Kws,
    float* __restrict__ Vws, float* __restrict__ Gws)
{
    const int b = blockIdx.x;
    const int s = threadIdx.x;

    float xr[CQKV];
    const float* xrow = X + (b * SS + s) * CQKV;
#pragma unroll
    for (int k4 = 0; k4 < CQKV / 4; ++k4) {
        const float4 v = ((const float4*)xrow)[k4];
        xr[k4 * 4 + 0] = v.x; xr[k4 * 4 + 1] = v.y;
        xr[k4 * 4 + 2] = v.z; xr[k4 * 4 + 3] = v.w;
    }
    const float scale = 0.17677669529663687f;  // 1/sqrt(32)

    for (int n4 = 0; n4 < 128; ++n4) {  // 4 output channels at a time
        float acc0 = 0.f, acc1 = 0.f, acc2 = 0.f, acc3 = 0.f;
        const float* w0 = W + (n4 * 4 + 0) * CQKV;
        const float* w1 = W + (n4 * 4 + 1) * CQKV;
        const float* w2 = W + (n4 * 4 + 2) * CQKV;
        const float* w3 = W + (n4 * 4 + 3) * CQKV;
#pragma unroll
        for (int k = 0; k < CQKV; ++k) {
            const float x = xr[k];
            acc0 += x * w0[k];
            acc1 += x * w1[k];
            acc2 += x * w2[k];
            acc3 += x * w3[k];
        }
        float accs[4] = {acc0, acc1, acc2, acc3};
#pragma unroll
        for (int j = 0; j < 4; ++j) {
            const int n = n4 * 4 + j;
            const int which = n >> 7;
            const int h = (n >> 5) & 3;
            const int ci = n & 31;
            const int dst = ((b * NH + h) * SS + s) * CH + ci;
            const float v = accs[j];
            if (which == 0)      Qws[dst] = v * scale;
            else if (which == 1) Kws[dst] = v;
            else if (which == 2) Vws[dst] = v;
            else                 Gws[dst] = 1.f / (1.f + __expf(-(v + gbias[n & 127])));
        }
    }
}

// ---------------------------------------------------------------------------
// K2: attention core per (b,h). thread t <-> query row q=t.
// K/V rows fetched via the scalar path (wave-uniform address); bias tile
// staged coalesced into LDS. Chunked (32-wide) online softmax.
// ---------------------------------------------------------------------------
__global__ __launch_bounds__(256, 2) void k2_attn(
    const float* __restrict__ Qws, const float* __restrict__ Kws,
    const float* __restrict__ Vws, const float* __restrict__ Gws,
    const float* __restrict__ mask,  // [B][S]
    const float* __restrict__ bias,  // [NH][S][S]
    float* __restrict__ og)          // [B][S][HC]
{
    const int b = blockIdx.x;
    const int h = blockIdx.y;
    const int q = threadIdx.x;

    __shared__ float Bs[256 * 33];
    __shared__ float maskAdd[256];

    maskAdd[q] = (mask[b * SS + q] - 1.f) * 1e9f;

    float qv[32], gate[32];
    const int qbase = ((b * NH + h) * SS + q) * CH;
#pragma unroll
    for (int i = 0; i < 8; ++i) {
        const float4 v = ((const float4*)(Qws + qbase))[i];
        qv[i * 4 + 0] = v.x; qv[i * 4 + 1] = v.y;
        qv[i * 4 + 2] = v.z; qv[i * 4 + 3] = v.w;
    }
#pragma unroll
    for (int i = 0; i < 8; ++i) {
        const float4 v = ((const float4*)(Gws + qbase))[i];
        gate[i * 4 + 0] = v.x; gate[i * 4 + 1] = v.y;
        gate[i * 4 + 2] = v.z; gate[i * 4 + 3] = v.w;
    }

    float m = -1e30f, l = 0.f;
    float oacc[32];
#pragma unroll
    for (int ci = 0; ci < 32; ++ci) oacc[ci] = 0.f;

    for (int kc = 0; kc < 8; ++kc) {
        __syncthreads();
        // stage bias tile [256 q][32 k], padded stride 33
#pragma unroll
        for (int i = 0; i < 8; ++i) {
            const int e = i * 256 + threadIdx.x;  // 2048 float4
            const int qq = e >> 3, k4 = e & 7;
            const float4 v = *(const float4*)(bias + (h * SS + qq) * SS + kc * 32 + k4 * 4);
            Bs[qq * 33 + k4 * 4 + 0] = v.x;
            Bs[qq * 33 + k4 * 4 + 1] = v.y;
            Bs[qq * 33 + k4 * 4 + 2] = v.z;
            Bs[qq * 33 + k4 * 4 + 3] = v.w;
        }
        __syncthreads();

        float skk[32];
#pragma unroll
        for (int kk = 0; kk < 32; ++kk) {
            const int ka = kc * 32 + kk;
            const int kb = __builtin_amdgcn_readfirstlane(((b * NH + h) * SS + ka) * CH);
            float sc = 0.f;
#pragma unroll
            for (int ci = 0; ci < 32; ++ci) sc += qv[ci] * Kws[kb + ci];
            skk[kk] = sc + Bs[q * 33 + kk] + maskAdd[ka];
        }
        float cm = skk[0];
#pragma unroll
        for (int kk = 1; kk < 32; ++kk) cm = fmaxf(cm, skk[kk]);
        const float mnew = fmaxf(m, cm);
        const float alpha = __expf(m - mnew);
        l *= alpha;
#pragma unroll
        for (int ci = 0; ci < 32; ++ci) oacc[ci] *= alpha;
        m = mnew;

#pragma unroll
        for (int kk = 0; kk < 32; ++kk) {
            const float p = __expf(skk[kk] - m);
            l += p;
            const int ka = kc * 32 + kk;
            const int vb = __builtin_amdgcn_readfirstlane(((b * NH + h) * SS + ka) * CH);
#pragma unroll
            for (int ci = 0; ci < 32; ++ci) oacc[ci] += p * Vws[vb + ci];
        }
    }

    const float inv = 1.f / l;
    const int ob = (b * SS + q) * HC + h * CH;
#pragma unroll
    for (int i = 0; i < 8; ++i) {
        float4 v;
        v.x = oacc[i * 4 + 0] * inv * gate[i * 4 + 0];
        v.y = oacc[i * 4 + 1] * inv * gate[i * 4 + 1];
        v.z = oacc[i * 4 + 2] * inv * gate[i * 4 + 2];
        v.w = oacc[i * 4 + 3] * inv * gate[i * 4 + 3];
        *((float4*)(og + ob + i * 4)) = v;
    }
}

// ---------------------------------------------------------------------------
// K3: out[0,i,j,c] = add[0,i,j,c] + b_o[c] + sum_f og[j,i,f] * Wo[c,f]
// grid 1024: i = bx>>2 (s), jt = bx&3. threads: jj = t&63 (b-index within
// tile), cq = t>>6 (wave-uniform c-quarter -> scalar W_o loads).
// ---------------------------------------------------------------------------
__global__ __launch_bounds__(256, 2) void k3_proj(
    const float* __restrict__ og,   // [B][S][HC]
    const float* __restrict__ Wo,   // [128][128]
    const float* __restrict__ bo,   // [128]
    const float* __restrict__ addt, // [S][B][128] indexing (i*256+j)*128+c
    float* __restrict__ out)
{
    const int i  = blockIdx.x >> 2;
    const int jt = blockIdx.x & 3;
    const int jj = threadIdx.x & 63;
    const int cq = threadIdx.x >> 6;
    const int j  = jt * 64 + jj;

    __shared__ float OgS[64 * 129];

#pragma unroll
    for (int it = 0; it < 8; ++it) {
        const int e = it * 256 + threadIdx.x;  // 2048 float4 = 64 rows x 128 f
        const int r = e >> 5, f4 = e & 31;
        const float4 v = *(const float4*)(og + ((jt * 64 + r) * SS + i) * HC + f4 * 4);
        OgS[r * 129 + f4 * 4 + 0] = v.x;
        OgS[r * 129 + f4 * 4 + 1] = v.y;
        OgS[r * 129 + f4 * 4 + 2] = v.z;
        OgS[r * 129 + f4 * 4 + 3] = v.w;
    }
    __syncthreads();

    float acc[32];
#pragma unroll
    for (int c = 0; c < 32; ++c) acc[c] = 0.f;

#pragma unroll 4
    for (int f = 0; f < HC; ++f) {
        const float v = OgS[jj * 129 + f];
#pragma unroll
        for (int c = 0; c < 32; ++c)
            acc[c] += v * Wo[(cq * 32 + c) * HC + f];
    }

    const int ob = (i * BB + j) * CQKV + cq * 32;
#pragma unroll
    for (int c4 = 0; c4 < 8; ++c4) {
        const float4 a = *(const float4*)(addt + ob + c4 * 4);
        float4 o;
        o.x = acc[c4 * 4 + 0] + bo[cq * 32 + c4 * 4 + 0] + a.x;
        o.y = acc[c4 * 4 + 1] + bo[cq * 32 + c4 * 4 + 1] + a.y;
        o.z = acc[c4 * 4 + 2] + bo[cq * 32 + c4 * 4 + 2] + a.z;
        o.w = acc[c4 * 4 + 3] + bo[cq * 32 + c4 * 4 + 3] + a.w;
        *((float4*)(out + ob + c4 * 4)) = o;
    }
}

extern "C" void kernel_launch(void* const* d_in, const int* in_sizes, int n_in,
                              void* d_out, int out_size, void* d_ws, size_t ws_size,
                              hipStream_t stream) {
    const float* X     = (const float*)d_in[0];  // input_qkv  [1,256,256,128]
    const float* mask  = (const float*)d_in[1];  // [1,256,1,1,256]
    const float* bias  = (const float*)d_in[2];  // [1,1,4,256,256]
    const float* addt  = (const float*)d_in[3];  // [1,256,256,128]
    const float* Wqkvg = (const float*)d_in[4];  // [512,128]
    const float* gbias = (const float*)d_in[5];  // [128]
    const float* Wo    = (const float*)d_in[6];  // [128,128]
    const float* bo    = (const float*)d_in[7];  // [128]
    float* out = (float*)d_out;

    const size_t T = (size_t)BB * NH * SS * CH;  // 8,388,608 floats per tensor
    float* Qws = (float*)d_ws;
    float* Kws = Qws + T;
    float* Vws = Kws + T;
    float* Gws = Vws + T;
    float* og  = Gws + T;

    k1_qkvg<<<BB, 256, 0, stream>>>(X, Wqkvg, gbias, Qws, Kws, Vws, Gws);
    k2_attn<<<dim3(BB, NH), 256, 0, stream>>>(Qws, Kws, Vws, Gws, mask, bias, og);
    k3_proj<<<SS * 4, 256, 0, stream>>>(og, Wo, bo, addt, out);
}

// Round 2
// 299.203 us; speedup vs baseline: 7.0901x; 7.0901x over previous
//
#include <hip/hip_runtime.h>
#include <math.h>

#define BB 256
#define SS 256
#define NH 4

typedef __attribute__((ext_vector_type(8))) short bfrag;   // 8 bf16 (4 VGPRs)
typedef __attribute__((ext_vector_type(4))) float ffrag;   // 4 fp32 acc

__device__ inline unsigned short f2bf(float x) {
    unsigned u = __float_as_uint(x);
    u += 0x7FFF + ((u >> 16) & 1);          // round-to-nearest-even
    return (unsigned short)(u >> 16);
}
__device__ inline float bf2f(unsigned short h) {
    return __uint_as_float(((unsigned)h) << 16);
}
__device__ inline unsigned pack2(float a, float b) {
    return (unsigned)f2bf(a) | ((unsigned)f2bf(b) << 16);
}
__device__ inline bfrag pack_frag(float4 a, float4 b) {
    bfrag f;
    f[0] = (short)f2bf(a.x); f[1] = (short)f2bf(a.y);
    f[2] = (short)f2bf(a.z); f[3] = (short)f2bf(a.w);
    f[4] = (short)f2bf(b.x); f[5] = (short)f2bf(b.y);
    f[6] = (short)f2bf(b.z); f[7] = (short)f2bf(b.w);
    return f;
}

// ---------------------------------------------------------------------------
// Fused QKVG projection + attention per (b,h) block. 256 threads = 4 waves;
// wave w owns s/q rows [64w, 64w+64).
// Layout facts (verified, cdna_hip_programming.md §3): 16x16x32 bf16 MFMA:
//   A-frag: m = lane&15, k = (lane>>4)*8 + j      (8 contiguous-k bf16)
//   B-frag: n = lane&15, k = (lane>>4)*8 + j      (reads Bt[n][k] rows)
//   C/D:    row(m) = (lane>>4)*4 + reg, col(n) = lane&15
// We compute S^T = K·Q^T (A=K rows, B=Q rows) so softmax over k is a
// register + shfl_xor(16/32) reduction per column q, and P (written [q][k]
// to LDS) re-enters PV as the B operand of O^T = V^T·P^T (A=Vt rows).
// ---------------------------------------------------------------------------
__global__ __launch_bounds__(256, 1) void k_fused(
    const float* __restrict__ X,      // [B][S][128]
    const float* __restrict__ W,      // [512][128]
    const float* __restrict__ gbias,  // [128]
    const float* __restrict__ mask,   // [B][S] (k-indexed)
    const float* __restrict__ bias,   // [NH][S][S]
    unsigned short* __restrict__ og)  // bf16 [B][S][128]
{
    const int b = blockIdx.x, h = blockIdx.y;
    const int t = threadIdx.x;
    const int w = t >> 6, lane = t & 63, l15 = lane & 15, quad = lane >> 4;

    __shared__ unsigned short Qb[SS * 40];     // [s][c] stride 40 (16B-aligned rows)
    __shared__ unsigned short Kb[SS * 40];
    __shared__ unsigned short Vt[32 * 264];    // [c][s] stride 264
    __shared__ unsigned short Gb[SS * 34];     // [s][c] stride 34
    __shared__ unsigned short Pb[4][16 * 264]; // per-wave [q][k] stride 264
    __shared__ float maskLds[SS];

    maskLds[t] = (mask[b * SS + t] - 1.0f) * 1e9f;

    const float qscale = 0.17677669529663687f;  // 1/sqrt(32)

    // ---------------- phase A: QKVG projection for head h ----------------
    for (int half = 0; half < 2; ++half) {
        bfrag Wfr[4][4];
#pragma unroll
        for (int f4 = 0; f4 < 4; ++f4) {
            const int floc = (half * 4 + f4) * 16 + l15;            // 0..127
            const int grow = (floc >> 5) * 128 + h * 32 + (floc & 31);
#pragma unroll
            for (int cc = 0; cc < 4; ++cc) {
                const float* p = W + grow * 128 + cc * 32 + quad * 8;
                Wfr[f4][cc] = pack_frag(*(const float4*)p, *(const float4*)(p + 4));
            }
        }
#pragma unroll
        for (int st = 0; st < 4; ++st) {
            const int s = w * 64 + st * 16 + l15;
            bfrag Xfr[4];
#pragma unroll
            for (int cc = 0; cc < 4; ++cc) {
                const float* p = X + (b * SS + s) * 128 + cc * 32 + quad * 8;
                Xfr[cc] = pack_frag(*(const float4*)p, *(const float4*)(p + 4));
            }
#pragma unroll
            for (int f4 = 0; f4 < 4; ++f4) {
                ffrag D = {0.f, 0.f, 0.f, 0.f};
#pragma unroll
                for (int cc = 0; cc < 4; ++cc)
                    D = __builtin_amdgcn_mfma_f32_16x16x32_bf16(Xfr[cc], Wfr[f4][cc], D, 0, 0, 0);
                const int ft = half * 4 + f4;
                const int fcol = ft * 16 + l15;
#pragma unroll
                for (int r = 0; r < 4; ++r) {
                    const int srow = w * 64 + st * 16 + quad * 4 + r;
                    const float v = D[r];
                    if (ft < 2)       Qb[srow * 40 + fcol] = f2bf(v * qscale);
                    else if (ft < 4)  Kb[srow * 40 + (fcol - 32)] = f2bf(v);
                    else if (ft < 6)  Vt[(fcol - 64) * 264 + srow] = f2bf(v);
                    else {
                        const int c = fcol - 96;
                        const float g = 1.0f / (1.0f + __expf(-(v + gbias[h * 32 + c])));
                        Gb[srow * 34 + c] = f2bf(g);
                    }
                }
            }
        }
    }
    __syncthreads();

    // ---------------- phase B: attention ----------------
    bfrag Vfr[2][8];   // A-frags of V^T, loop-invariant
#pragma unroll
    for (int ch = 0; ch < 2; ++ch)
#pragma unroll
        for (int ck = 0; ck < 8; ++ck)
            Vfr[ch][ck] = *(const bfrag*)&Vt[(ch * 16 + l15) * 264 + ck * 32 + quad * 8];

    for (int qq = 0; qq < 4; ++qq) {
        const int q = w * 64 + qq * 16 + l15;
        const bfrag Qfr = *(const bfrag*)&Qb[q * 40 + quad * 8];

        ffrag S[16];
#pragma unroll
        for (int kt = 0; kt < 16; ++kt) {
            const bfrag Kfr = *(const bfrag*)&Kb[(kt * 16 + l15) * 40 + quad * 8];
            const ffrag z = {0.f, 0.f, 0.f, 0.f};
            S[kt] = __builtin_amdgcn_mfma_f32_16x16x32_bf16(Kfr, Qfr, z, 0, 0, 0);
        }

        // bias + mask, running max (lane's column q fixed; rows k = kt*16+quad*4+r)
        const float* brow = bias + (h * SS + q) * SS;
        float m = -1e30f;
#pragma unroll
        for (int kt = 0; kt < 16; ++kt) {
            const float4 bv = *(const float4*)(brow + kt * 16 + quad * 4);
            const float4 mv = *(const float4*)(maskLds + kt * 16 + quad * 4);
            S[kt][0] += bv.x + mv.x; S[kt][1] += bv.y + mv.y;
            S[kt][2] += bv.z + mv.z; S[kt][3] += bv.w + mv.w;
            m = fmaxf(m, fmaxf(fmaxf(S[kt][0], S[kt][1]), fmaxf(S[kt][2], S[kt][3])));
        }
        m = fmaxf(m, __shfl_xor(m, 16, 64));
        m = fmaxf(m, __shfl_xor(m, 32, 64));

        float l = 0.f;
#pragma unroll
        for (int kt = 0; kt < 16; ++kt) {
#pragma unroll
            for (int r = 0; r < 4; ++r) {
                const float p = __expf(S[kt][r] - m);
                S[kt][r] = p;
                l += p;
            }
        }
        l += __shfl_xor(l, 16, 64);
        l += __shfl_xor(l, 32, 64);

        // P -> LDS [q][k] bf16 (pairs: regs r,r+1 are adjacent k)
#pragma unroll
        for (int kt = 0; kt < 16; ++kt) {
            const int base = l15 * 264 + kt * 16 + quad * 4;
            *(unsigned*)&Pb[w][base]     = pack2(S[kt][0], S[kt][1]);
            *(unsigned*)&Pb[w][base + 2] = pack2(S[kt][2], S[kt][3]);
        }

        ffrag O[2];
        O[0] = (ffrag){0.f, 0.f, 0.f, 0.f};
        O[1] = (ffrag){0.f, 0.f, 0.f, 0.f};
#pragma unroll
        for (int ck = 0; ck < 8; ++ck) {
            const bfrag Pfr = *(const bfrag*)&Pb[w][l15 * 264 + ck * 32 + quad * 8];
            O[0] = __builtin_amdgcn_mfma_f32_16x16x32_bf16(Vfr[0][ck], Pfr, O[0], 0, 0, 0);
            O[1] = __builtin_amdgcn_mfma_f32_16x16x32_bf16(Vfr[1][ck], Pfr, O[1], 0, 0, 0);
        }

        const float invl = 1.0f / l;
        const unsigned short* gr = &Gb[q * 34];
        unsigned* orow = (unsigned*)(og + (b * SS + q) * 128 + h * 32);
#pragma unroll
        for (int ch = 0; ch < 2; ++ch) {
            const int c0 = ch * 16 + quad * 4;
            const float v0 = O[ch][0] * invl * bf2f(gr[c0 + 0]);
            const float v1 = O[ch][1] * invl * bf2f(gr[c0 + 1]);
            const float v2 = O[ch][2] * invl * bf2f(gr[c0 + 2]);
            const float v3 = O[ch][3] * invl * bf2f(gr[c0 + 3]);
            orow[(c0 >> 1) + 0] = pack2(v0, v1);
            orow[(c0 >> 1) + 1] = pack2(v2, v3);
        }
    }
}

// ---------------------------------------------------------------------------
// K3: out[i,j,c] = addt[i,j,c] + bo[c] + sum_f og[j][i][f] * Wo[c][f]
// block (i, jt): 64 j x 128 c tile. og bf16 rows are direct A-frags.
// ---------------------------------------------------------------------------
__global__ __launch_bounds__(256, 2) void k3_proj(
    const unsigned short* __restrict__ ogb,  // bf16 [B][S][128]
    const float* __restrict__ Wo,            // [128][128]
    const float* __restrict__ bo,            // [128]
    const float* __restrict__ addt,          // [S][B][128]
    float* __restrict__ out)                 // [S][B][128]
{
    const int i = blockIdx.x, jt = blockIdx.y;
    const int t = threadIdx.x;
    const int w = t >> 6, lane = t & 63, l15 = lane & 15, quad = lane >> 4;

    __shared__ unsigned short WoS[128 * 136];  // [c][f] bf16, stride 136

#pragma unroll
    for (int it = 0; it < 16; ++it) {
        const int e = it * 256 + t;           // 4096 float4 chunks
        const int row = e >> 5, c4 = e & 31;
        const float4 v = *(const float4*)(Wo + row * 128 + c4 * 4);
        *(unsigned*)&WoS[row * 136 + c4 * 4]     = pack2(v.x, v.y);
        *(unsigned*)&WoS[row * 136 + c4 * 4 + 2] = pack2(v.z, v.w);
    }
    __syncthreads();

    const int j0 = jt * 64 + w * 16;
    bfrag A[4];
#pragma unroll
    for (int cc = 0; cc < 4; ++cc)
        A[cc] = *(const bfrag*)(ogb + ((j0 + l15) * SS + i) * 128 + cc * 32 + quad * 8);

#pragma unroll
    for (int ct = 0; ct < 8; ++ct) {
        ffrag D = {0.f, 0.f, 0.f, 0.f};
#pragma unroll
        for (int cc = 0; cc < 4; ++cc) {
            const bfrag Bf = *(const bfrag*)&WoS[(ct * 16 + l15) * 136 + cc * 32 + quad * 8];
            D = __builtin_amdgcn_mfma_f32_16x16x32_bf16(A[cc], Bf, D, 0, 0, 0);
        }
        const float bov = bo[ct * 16 + l15];
#pragma unroll
        for (int r = 0; r < 4; ++r) {
            const int j = j0 + quad * 4 + r;
            const int idx = (i * BB + j) * 128 + ct * 16 + l15;
            out[idx] = D[r] + bov + addt[idx];
        }
    }
}

extern "C" void kernel_launch(void* const* d_in, const int* in_sizes, int n_in,
                              void* d_out, int out_size, void* d_ws, size_t ws_size,
                              hipStream_t stream) {
    const float* X     = (const float*)d_in[0];  // input_qkv [1,256,256,128]
    const float* mask  = (const float*)d_in[1];  // [1,256,1,1,256]
    const float* bias  = (const float*)d_in[2];  // [1,1,4,256,256]
    const float* addt  = (const float*)d_in[3];  // [1,256,256,128]
    const float* Wqkvg = (const float*)d_in[4];  // [512,128]
    const float* gbias = (const float*)d_in[5];  // [128]
    const float* Wo    = (const float*)d_in[6];  // [128,128]
    const float* bo    = (const float*)d_in[7];  // [128]
    float* out = (float*)d_out;

    unsigned short* og = (unsigned short*)d_ws;  // bf16 [B][S][128] = 16.7 MB

    k_fused<<<dim3(BB, NH), 256, 0, stream>>>(X, Wqkvg, gbias, mask, bias, og);
    k3_proj<<<dim3(SS, 4), 256, 0, stream>>>(og, Wo, bo, addt, out);
}

// Round 3
// 234.716 us; speedup vs baseline: 9.0380x; 1.2747x over previous
//
#include <hip/hip_runtime.h>
#include <math.h>

#define BB 256
#define SS 256
#define NH 4

typedef __attribute__((ext_vector_type(8))) short bfrag;   // 8 bf16 (4 VGPRs)
typedef __attribute__((ext_vector_type(4))) float ffrag;   // 4 fp32 acc

__device__ inline unsigned short f2bf(float x) {
    unsigned u = __float_as_uint(x);
    u += 0x7FFF + ((u >> 16) & 1);          // round-to-nearest-even
    return (unsigned short)(u >> 16);
}
__device__ inline float bf2f(unsigned short h) {
    return __uint_as_float(((unsigned)h) << 16);
}
__device__ inline unsigned pack2(float a, float b) {
    return (unsigned)f2bf(a) | ((unsigned)f2bf(b) << 16);
}
union FragU { unsigned u[4]; bfrag b; };

// ws layout (bf16 elements):
//   Xb  at 0         [B][S][128]   8388608
//   Wb  at 8388608   [512][128]      65536
//   Wob at 8454144   [128][128]      16384
//   og  at 8470528   [B][S][128]   8388608
#define XB_OFF  0
#define WB_OFF  8388608
#define WOB_OFF 8454144
#define OG_OFF  8470528

// ---------------------------------------------------------------------------
// k0: cast X, W_qkvg, W_o from fp32 to bf16 into workspace. 8 elems/thread.
// ---------------------------------------------------------------------------
__global__ __launch_bounds__(256) void k0_cast(
    const float* __restrict__ X, const float* __restrict__ W,
    const float* __restrict__ Wo, unsigned short* __restrict__ dst)
{
    const int gid = blockIdx.x * 256 + threadIdx.x;
    const int XN8 = 8388608 / 8, WN8 = 65536 / 8, WoN8 = 16384 / 8;
    const float* src;
    size_t soff, doff;
    if (gid < XN8)            { src = X;  soff = (size_t)gid * 8;                 doff = XB_OFF + soff; }
    else if (gid < XN8 + WN8) { src = W;  soff = (size_t)(gid - XN8) * 8;         doff = WB_OFF + soff; }
    else if (gid < XN8 + WN8 + WoN8) { src = Wo; soff = (size_t)(gid - XN8 - WN8) * 8; doff = WOB_OFF + soff; }
    else return;
    const float4 a = *(const float4*)(src + soff);
    const float4 b = *(const float4*)(src + soff + 4);
    unsigned r0 = pack2(a.x, a.y), r1 = pack2(a.z, a.w);
    unsigned r2 = pack2(b.x, b.y), r3 = pack2(b.z, b.w);
    uint4 o; o.x = r0; o.y = r1; o.z = r2; o.w = r3;
    *(uint4*)(dst + doff) = o;
}

// ---------------------------------------------------------------------------
// Fused QKVG projection + attention per (b,h). 256 thr = 4 waves; wave w owns
// s/q rows [64w, 64w+64). 16x16x32 bf16 MFMA layouts:
//   A/B-frag: row = lane&15, k = (lane>>4)*8 + j
//   C/D:      row = (lane>>4)*4 + reg, col = lane&15
// S^T = K·Q^T  (softmax over k = per-lane regs + shfl_xor(16/32) over cols).
// P (C-layout, col q = l15) -> PV B-frag via cross-quad shuffles (no LDS).
// O^T = V^T·P^T.  LDS total 74.5 KB -> 2 blocks/CU.
// ---------------------------------------------------------------------------
__global__ __launch_bounds__(256, 2) void k_fused(
    const unsigned short* __restrict__ Xb,   // bf16 [B][S][128]
    const unsigned short* __restrict__ Wb,   // bf16 [512][128]
    const float* __restrict__ gbias,         // [128]
    const float* __restrict__ mask,          // [B][S] (k-indexed)
    const float* __restrict__ bias,          // [NH][S][S]
    unsigned short* __restrict__ og)         // bf16 [B][S][128]
{
    const int h = blockIdx.x, b = blockIdx.y;
    const int t = threadIdx.x;
    const int w = t >> 6, lane = t & 63, l15 = lane & 15, quad = lane >> 4;

    __shared__ unsigned short Qb[SS * 40];   // [s][c] stride 40
    __shared__ unsigned short Kb[SS * 40];
    __shared__ unsigned short Vt[32 * 264];  // [c][s] stride 264
    __shared__ unsigned short Gb[SS * 34];   // [s][c] stride 34
    __shared__ float maskLds[SS];

    maskLds[t] = (mask[b * SS + t] - 1.0f) * 1e9f;

    const float qscale = 0.17677669529663687f;  // 1/sqrt(32)

    // ---------------- phase A: QKVG projection for head h ----------------
    for (int half = 0; half < 2; ++half) {
        bfrag Wfr[4][4];
#pragma unroll
        for (int f4 = 0; f4 < 4; ++f4) {
            const int floc = (half * 4 + f4) * 16 + l15;            // 0..127
            const int grow = (floc >> 5) * 128 + h * 32 + (floc & 31);
#pragma unroll
            for (int cc = 0; cc < 4; ++cc)
                Wfr[f4][cc] = *(const bfrag*)(Wb + grow * 128 + cc * 32 + quad * 8);
        }
#pragma unroll
        for (int st = 0; st < 4; ++st) {
            const int s = w * 64 + st * 16 + l15;
            bfrag Xfr[4];
#pragma unroll
            for (int cc = 0; cc < 4; ++cc)
                Xfr[cc] = *(const bfrag*)(Xb + (b * SS + s) * 128 + cc * 32 + quad * 8);
#pragma unroll
            for (int f4 = 0; f4 < 4; ++f4) {
                ffrag D = {0.f, 0.f, 0.f, 0.f};
#pragma unroll
                for (int cc = 0; cc < 4; ++cc)
                    D = __builtin_amdgcn_mfma_f32_16x16x32_bf16(Xfr[cc], Wfr[f4][cc], D, 0, 0, 0);
                const int ft = half * 4 + f4;
                const int fcol = ft * 16 + l15;
                const int srow0 = w * 64 + st * 16 + quad * 4;
                if (ft < 2) {
#pragma unroll
                    for (int r = 0; r < 4; ++r)
                        Qb[(srow0 + r) * 40 + fcol] = f2bf(D[r] * qscale);
                } else if (ft < 4) {
#pragma unroll
                    for (int r = 0; r < 4; ++r)
                        Kb[(srow0 + r) * 40 + (fcol - 32)] = f2bf(D[r]);
                } else if (ft < 6) {
                    const int base = (fcol - 64) * 264 + srow0;
                    *(unsigned*)&Vt[base]     = pack2(D[0], D[1]);
                    *(unsigned*)&Vt[base + 2] = pack2(D[2], D[3]);
                } else {
                    const int c = fcol - 96;
                    const float gb = gbias[h * 32 + c];
#pragma unroll
                    for (int r = 0; r < 4; ++r) {
                        const float g = 1.0f / (1.0f + __expf(-(D[r] + gb)));
                        Gb[(srow0 + r) * 34 + c] = f2bf(g);
                    }
                }
            }
        }
    }
    __syncthreads();

    // ---------------- phase B: attention ----------------
    bfrag Vfr[2][8];   // A-frags of V^T, loop-invariant
#pragma unroll
    for (int ch = 0; ch < 2; ++ch)
#pragma unroll
        for (int ck = 0; ck < 8; ++ck)
            Vfr[ch][ck] = *(const bfrag*)&Vt[(ch * 16 + l15) * 264 + ck * 32 + quad * 8];

    const int srcA = l15 + ((quad & 1) * 2) * 16;
    const int srcB = srcA + 16;
    const bool hi = (quad >> 1) != 0;

    for (int qq = 0; qq < 4; ++qq) {
        const int q = w * 64 + qq * 16 + l15;
        const bfrag Qfr = *(const bfrag*)&Qb[q * 40 + quad * 8];

        ffrag S[16];
#pragma unroll
        for (int kt = 0; kt < 16; ++kt) {
            const bfrag Kfr = *(const bfrag*)&Kb[(kt * 16 + l15) * 40 + quad * 8];
            const ffrag z = {0.f, 0.f, 0.f, 0.f};
            S[kt] = __builtin_amdgcn_mfma_f32_16x16x32_bf16(Kfr, Qfr, z, 0, 0, 0);
        }

        // + bias + mask; running max (lane owns column q; rows k=kt*16+quad*4+r)
        const float* brow = bias + (h * SS + q) * SS;
        float m = -1e30f;
#pragma unroll
        for (int kt = 0; kt < 16; ++kt) {
            const float4 bv = *(const float4*)(brow + kt * 16 + quad * 4);
            const float4 mv = *(const float4*)(maskLds + kt * 16 + quad * 4);
            S[kt][0] += bv.x + mv.x; S[kt][1] += bv.y + mv.y;
            S[kt][2] += bv.z + mv.z; S[kt][3] += bv.w + mv.w;
            m = fmaxf(m, fmaxf(fmaxf(S[kt][0], S[kt][1]), fmaxf(S[kt][2], S[kt][3])));
        }
        m = fmaxf(m, __shfl_xor(m, 16, 64));
        m = fmaxf(m, __shfl_xor(m, 32, 64));

        float l = 0.f;
        unsigned pk[16][2];   // P packed bf16 pairs (r01, r23), still C-layout
#pragma unroll
        for (int kt = 0; kt < 16; ++kt) {
            const float p0 = __expf(S[kt][0] - m);
            const float p1 = __expf(S[kt][1] - m);
            const float p2 = __expf(S[kt][2] - m);
            const float p3 = __expf(S[kt][3] - m);
            l += (p0 + p1) + (p2 + p3);
            pk[kt][0] = pack2(p0, p1);
            pk[kt][1] = pack2(p2, p3);
        }
        l += __shfl_xor(l, 16, 64);
        l += __shfl_xor(l, 32, 64);

        // C-layout -> B-frag transform via cross-quad shuffles.
        // B-frag word j01 of chunk ck needs P[ck*32+quad*8+{0,1}][q=l15] =
        // pk[2ck + (quad>>1)][0] from lane l15 + ((quad&1)*2 [+1 for j45])*16.
        ffrag O[2];
        O[0] = (ffrag){0.f, 0.f, 0.f, 0.f};
        O[1] = (ffrag){0.f, 0.f, 0.f, 0.f};
#pragma unroll
        for (int ck = 0; ck < 8; ++ck) {
            const unsigned a0 = (unsigned)__shfl((int)pk[2 * ck][0],     srcA, 64);
            const unsigned b0 = (unsigned)__shfl((int)pk[2 * ck + 1][0], srcA, 64);
            const unsigned a1 = (unsigned)__shfl((int)pk[2 * ck][1],     srcA, 64);
            const unsigned b1 = (unsigned)__shfl((int)pk[2 * ck + 1][1], srcA, 64);
            const unsigned a2 = (unsigned)__shfl((int)pk[2 * ck][0],     srcB, 64);
            const unsigned b2 = (unsigned)__shfl((int)pk[2 * ck + 1][0], srcB, 64);
            const unsigned a3 = (unsigned)__shfl((int)pk[2 * ck][1],     srcB, 64);
            const unsigned b3 = (unsigned)__shfl((int)pk[2 * ck + 1][1], srcB, 64);
            FragU fu;
            fu.u[0] = hi ? b0 : a0;
            fu.u[1] = hi ? b1 : a1;
            fu.u[2] = hi ? b2 : a2;
            fu.u[3] = hi ? b3 : a3;
            O[0] = __builtin_amdgcn_mfma_f32_16x16x32_bf16(Vfr[0][ck], fu.b, O[0], 0, 0, 0);
            O[1] = __builtin_amdgcn_mfma_f32_16x16x32_bf16(Vfr[1][ck], fu.b, O[1], 0, 0, 0);
        }

        const float invl = 1.0f / l;
        const unsigned short* gr = &Gb[q * 34];
        unsigned* orow = (unsigned*)(og + (b * SS + q) * 128 + h * 32);
#pragma unroll
        for (int ch = 0; ch < 2; ++ch) {
            const int c0 = ch * 16 + quad * 4;
            const float v0 = O[ch][0] * invl * bf2f(gr[c0 + 0]);
            const float v1 = O[ch][1] * invl * bf2f(gr[c0 + 1]);
            const float v2 = O[ch][2] * invl * bf2f(gr[c0 + 2]);
            const float v3 = O[ch][3] * invl * bf2f(gr[c0 + 3]);
            orow[(c0 >> 1) + 0] = pack2(v0, v1);
            orow[(c0 >> 1) + 1] = pack2(v2, v3);
        }
    }
}

// ---------------------------------------------------------------------------
// k3: out[i,j,c] = addt[i,j,c] + bo[c] + sum_f og[j][i][f] * Wo[c][f]
// Block (i, jh): 128 j rows x all 128 c. og rows staged coalesced into LDS;
// Wo held as per-wave register B-frags (wave w owns c in [32w, 32w+32)).
// ---------------------------------------------------------------------------
__global__ __launch_bounds__(256, 2) void k3_proj(
    const unsigned short* __restrict__ ogb,  // bf16 [B][S][128]
    const unsigned short* __restrict__ Wob,  // bf16 [128][128]
    const float* __restrict__ bo,            // [128]
    const float* __restrict__ addt,          // [S][B][128] view
    float* __restrict__ out)                 // [S][B][128]
{
    const int i = blockIdx.x, jh = blockIdx.y;
    const int t = threadIdx.x;
    const int w = t >> 6, lane = t & 63, l15 = lane & 15, quad = lane >> 4;

    __shared__ unsigned short OgS[128 * 136];  // [j][f] stride 136

    // stage og[jh*128 + jj][i][0..128) -> LDS, 128B per thread
    {
        const int jj = t >> 1, hf = t & 1;
        const unsigned short* src = ogb + (((size_t)(jh * 128 + jj) * SS + i) * 128) + hf * 64;
        unsigned short* dst = &OgS[jj * 136 + hf * 64];
#pragma unroll
        for (int u = 0; u < 8; ++u)
            *(uint4*)(dst + u * 8) = *(const uint4*)(src + u * 8);
    }

    // per-wave Wo B-frags: c rows (w*2+ctl)*16 + l15
    bfrag Wfr[2][4];
#pragma unroll
    for (int ctl = 0; ctl < 2; ++ctl) {
        const int crow = (w * 2 + ctl) * 16 + l15;
#pragma unroll
        for (int cc = 0; cc < 4; ++cc)
            Wfr[ctl][cc] = *(const bfrag*)(Wob + crow * 128 + cc * 32 + quad * 8);
    }
    const float bo0 = bo[(w * 2 + 0) * 16 + l15];
    const float bo1 = bo[(w * 2 + 1) * 16 + l15];

    __syncthreads();

#pragma unroll
    for (int jt = 0; jt < 8; ++jt) {
        bfrag Ab[4];
#pragma unroll
        for (int cc = 0; cc < 4; ++cc)
            Ab[cc] = *(const bfrag*)&OgS[(jt * 16 + l15) * 136 + cc * 32 + quad * 8];

        ffrag D0 = {0.f, 0.f, 0.f, 0.f};
        ffrag D1 = {0.f, 0.f, 0.f, 0.f};
#pragma unroll
        for (int cc = 0; cc < 4; ++cc) {
            D0 = __builtin_amdgcn_mfma_f32_16x16x32_bf16(Ab[cc], Wfr[0][cc], D0, 0, 0, 0);
            D1 = __builtin_amdgcn_mfma_f32_16x16x32_bf16(Ab[cc], Wfr[1][cc], D1, 0, 0, 0);
        }

        const int c0 = (w * 2 + 0) * 16 + l15;
        const int c1 = (w * 2 + 1) * 16 + l15;
#pragma unroll
        for (int r = 0; r < 4; ++r) {
            const int j = jh * 128 + jt * 16 + quad * 4 + r;
            const size_t row = (size_t)(i * BB + j) * 128;
            out[row + c0] = D0[r] + bo0 + addt[row + c0];
            out[row + c1] = D1[r] + bo1 + addt[row + c1];
        }
    }
}

extern "C" void kernel_launch(void* const* d_in, const int* in_sizes, int n_in,
                              void* d_out, int out_size, void* d_ws, size_t ws_size,
                              hipStream_t stream) {
    const float* X     = (const float*)d_in[0];  // input_qkv [1,256,256,128]
    const float* mask  = (const float*)d_in[1];  // [1,256,1,1,256]
    const float* bias  = (const float*)d_in[2];  // [1,1,4,256,256]
    const float* addt  = (const float*)d_in[3];  // [1,256,256,128]
    const float* Wqkvg = (const float*)d_in[4];  // [512,128]
    const float* gbias = (const float*)d_in[5];  // [128]
    const float* Wo    = (const float*)d_in[6];  // [128,128]
    const float* bo    = (const float*)d_in[7];  // [128]
    float* out = (float*)d_out;

    unsigned short* ws = (unsigned short*)d_ws;
    unsigned short* Xb  = ws + XB_OFF;
    unsigned short* Wb  = ws + WB_OFF;
    unsigned short* Wob = ws + WOB_OFF;
    unsigned short* og  = ws + OG_OFF;

    k0_cast<<<4136, 256, 0, stream>>>(X, Wqkvg, Wo, ws);
    k_fused<<<dim3(NH, BB), 256, 0, stream>>>(Xb, Wb, gbias, mask, bias, og);
    k3_proj<<<dim3(SS, 2), 256, 0, stream>>>(og, Wob, bo, addt, out);
}